// Round 5
// baseline (240.259 us; speedup 1.0000x reference)
//
#include <hip/hip_runtime.h>

// NonSpikingInput: RK2 leaky integrator, closed form per step:
//   v' = 0.625*v + 0.075*i   (E_REST = I_BIAS = 0)
// Output = full history, (4096, 8192) fp32. Memory-bound: 268 MB -> ~43 us floor.
//
// R3: LDS round-trip, phase barriers. 80.7 us, 2.5 TB/s.
// R4 FAILED-NEUTRAL: persistent pipeline, counted waitcnt. 81.8 us.
// R5 FAILED-NEUTRAL: 8 blocks/CU occupancy. 79.1 us.
// R6 FAILED-NEUTRAL: wave-level affine scan, no LDS/barriers, NT. 88 us.
// R7 FAILED-NEUTRAL: plain stores (WRITE_SIZE normalized 148->132 MB, so NT
//   amplification was real but not the limiter) + SEG=1024. 86 us, 2.4 TB/s.
// R8 change: per-wave MLP DEPTH. Every prior version keeps <=5 loads (~4 KB)
//   in flight per wave, then runs a ~600-cycle serial FMA/shuffle chain with
//   ZERO VMEM outstanding -> achieved in-flight bytes/CU sits below the
//   ~22 KB Little's-law requirement for 6.3 TB/s. Now: SEG=2048, 32 floats
//   per lane, 8 independent b128 loads issued back-to-back (32 KB/wave in
//   flight, 8x R7) consumed via incremental vmcnt. Lane decay A^32 -> scan is
//   only 3 shuffle steps (dist>=8 weight A^256 < 1e-38 == 0 in fp32; history
//   truncation policy is already A^64 ~ 9e-14, unchanged -> same absmax).
//   VGPR ~64-90 -> __launch_bounds__(256,4), 16 waves/CU: half the waves,
//   8x depth each. Pre-committed: if still ~80-88 us, ~3.1 TB/s effective is
//   the platform's mixed-stream rate for this pattern -> ROOFLINE.

typedef float fx4 __attribute__((ext_vector_type(4)));

constexpr int TT  = 8192;   // time steps per row
constexpr int BLK = 256;    // threads per block (4 waves)
constexpr int SEG = 2048;   // steps per wave-segment = 32 floats/lane
constexpr int NV  = 8;      // fx4 per lane
constexpr int WPB = BLK / 64;

__global__ __launch_bounds__(BLK, 4)
void neuron_scan(const float* __restrict__ in, float* __restrict__ out,
                 int nseg) {
    const float A    = 0.625f;
    const float Bc   = 0.075f;
    const float A4   = 0.152587890625f;            // exact in fp32
    const float A8   = 2.32830643653869629e-2f;
    const float A16  = 5.42101086242752217e-4f;
    const float A32  = 2.93873587705571877e-7f;    // per-lane decay
    const float A64  = 8.63616855509444463e-14f;
    const float A128 = 7.45834073120020674e-27f;

    const int lane = threadIdx.x & 63;
    const int wid  = blockIdx.x * WPB + (threadIdx.x >> 6);
    const int nw   = gridDim.x * WPB;

    for (int s = wid; s < nseg; s += nw) {
        const int row = s >> 2;            // TT/SEG = 4 segments per row
        const int col = s & 3;
        const size_t base = (size_t)row * TT + (size_t)col * SEG;
        const fx4* src = (const fx4*)(in + base);

        // 8 independent coalesced b128 loads, all issued before any use.
        // Wave covers [base, base+8192B); lane owns 128 B = 32 steps.
        fx4 x[NV];
        #pragma unroll
        for (int k = 0; k < NV; ++k) x[k] = src[NV * lane + k];

        // Warm-up carry inputs: preceding 64 floats, lanes 0..15, 4 each.
        const bool wu = (col > 0);         // uniform branch
        fx4 wx = {0.0f, 0.0f, 0.0f, 0.0f};
        if (wu && lane < 16) wx = src[lane - 16];   // bytes [base-256, base)

        // Local contribution of this lane's 32 steps from v=0.
        // (fmaf(A, 0, b) == b exactly, so k=0 matches the explicit start.)
        float c = 0.0f;
        #pragma unroll
        for (int k = 0; k < NV; ++k) {
            c = fmaf(A, c, Bc * x[k].x);
            c = fmaf(A, c, Bc * x[k].y);
            c = fmaf(A, c, Bc * x[k].z);
            c = fmaf(A, c, Bc * x[k].w);
        }

        // Warm-up: 64-step exact history from v=0 (A^64 truncation, same
        // policy as R3-R7). 16-lane affine mini-scan, per-lane decay A^4.
        float vwarm = 0.0f;
        if (wu) {
            float cw;
            cw = Bc * wx.x;
            cw = fmaf(A, cw, Bc * wx.y);
            cw = fmaf(A, cw, Bc * wx.z);
            cw = fmaf(A, cw, Bc * wx.w);
            float u;
            u = __shfl_up(cw, 1); if (lane >= 1) cw = fmaf(A4,  u, cw);
            u = __shfl_up(cw, 2); if (lane >= 2) cw = fmaf(A8,  u, cw);
            u = __shfl_up(cw, 4); if (lane >= 4) cw = fmaf(A16, u, cw);
            u = __shfl_up(cw, 8); if (lane >= 8) cw = fmaf(A32, u, cw);
            vwarm = __shfl(cw, 15);        // inclusive over all 64 warm steps
        }
        if (lane == 0) c = fmaf(A32, vwarm, c);

        // Inclusive affine scan across lanes, per-lane decay A^32.
        // Distances >=8 carry weight A^256 < 1e-38 -> exactly 0 in fp32.
        float u;
        u = __shfl_up(c, 1); if (lane >= 1) c = fmaf(A32,  u, c);
        u = __shfl_up(c, 2); if (lane >= 2) c = fmaf(A64,  u, c);
        u = __shfl_up(c, 4); if (lane >= 4) c = fmaf(A128, u, c);

        // v entering this lane's first step = inclusive value of lane-1.
        float venter = __shfl_up(c, 1);
        if (lane == 0) venter = vwarm;

        // Re-run the 32 steps exactly from venter, emitting history in-place.
        float v = venter;
        #pragma unroll
        for (int k = 0; k < NV; ++k) {
            v = fmaf(A, v, Bc * x[k].x); x[k].x = v;
            v = fmaf(A, v, Bc * x[k].y); x[k].y = v;
            v = fmaf(A, v, Bc * x[k].z); x[k].z = v;
            v = fmaf(A, v, Bc * x[k].w); x[k].w = v;
        }

        // Coalesced plain stores, mirror of the loads.
        fx4* dst = (fx4*)(out + base);
        #pragma unroll
        for (int k = 0; k < NV; ++k) dst[NV * lane + k] = x[k];
    }
}

extern "C" void kernel_launch(void* const* d_in, const int* in_sizes, int n_in,
                              void* d_out, int out_size, void* d_ws, size_t ws_size,
                              hipStream_t stream) {
    const float* in = (const float*)d_in[0];
    float* out = (float*)d_out;
    const int n_rows = in_sizes[0] / TT;          // 4096
    const int nseg = n_rows * (TT / SEG);         // 16384
    int blocks = 1024;                            // 4 blocks/CU resident, 4 iters/wave
    if (blocks * WPB > nseg) blocks = (nseg + WPB - 1) / WPB;
    neuron_scan<<<dim3(blocks), dim3(BLK), 0, stream>>>(in, out, nseg);
}

// Round 6
// 237.785 us; speedup vs baseline: 1.0104x; 1.0104x over previous
//
#include <hip/hip_runtime.h>

// NonSpikingInput: RK2 leaky integrator, closed form per step:
//   v' = 0.625*v + 0.075*i   (E_REST = I_BIAS = 0)
// Output = full history, (4096, 8192) fp32. Memory-bound: 268 MB -> ~43 us floor.
//
// R3: LDS round-trip, phase barriers. 80.7 us, 2.5 TB/s.
// R4 FAILED-NEUTRAL: persistent pipeline + counted waitcnt (LDS). 81.8 us.
// R5 FAILED-NEUTRAL: 8 blocks/CU occupancy. 79.1 us.
// R6 FAILED-NEUTRAL: wave-level affine scan, no LDS/barriers, NT. 88 us.
// R7 FAILED-NEUTRAL: plain stores + SEG=1024. 86 us, 2.4 TB/s.
// R8 INVALID: SEG=2048 "8 loads in flight" -- VGPR_Count=28 proves the
//   compiler never held the depth (launch_bounds(256,4) reg cap -> serialized
//   load/consume + L1 re-loads). Depth was never actually tested.
// R9 change: barrier-free REGISTER DOUBLE-BUFFER -- the one shape difference
//   left vs the 6.3 TB/s copy ubench (m13): our waves always had a long
//   VMEM-silent FMA/shuffle window between load burst and store burst.
//   Now: prefetch segment s+nw into xb BEFORE computing segment s from xa
//   (sched_barrier(0) pins the prefetch above the compute), store, rotate
//   regs. Steady state: next loads in flight across the whole compute+store;
//   vmcnt wait only at rotation, a full iteration after issue. launch_bounds
//   (256,3) -> ~85 VGPR cap vs ~60 live (xa16+xb16+wx8+temps) so the
//   compiler can keep xb resident (R8's failure mode).
//   Validity gate: VGPR_Count >= 50. Pre-commit: if valid and still 80-92 us
//   -> ROOFLINE next round (fills are 150 us of the 230 us metric anyway).

typedef float fx4 __attribute__((ext_vector_type(4)));

constexpr int TT  = 8192;   // time steps per row
constexpr int BLK = 256;    // threads per block (4 waves)
constexpr int SEG = 1024;   // steps per wave-segment = 16 floats/lane
constexpr int NV  = 4;      // fx4 per lane
constexpr int WPB = BLK / 64;

__global__ __launch_bounds__(BLK, 3)
void neuron_scan(const float* __restrict__ in, float* __restrict__ out,
                 int nseg) {
    const float A    = 0.625f;
    const float Bc   = 0.075f;
    const float A4   = 0.152587890625f;            // exact in fp32
    const float A8   = 2.32830643653869629e-2f;
    const float A16  = 5.42101086242752217e-4f;    // per-lane decay (16 steps)
    const float A32  = 2.93873587705571877e-7f;
    const float A64  = 8.63616855509444463e-14f;
    const float A128 = 7.45834073120020674e-27f;

    const int lane = threadIdx.x & 63;
    const int wid  = blockIdx.x * WPB + (threadIdx.x >> 6);
    const int nw   = gridDim.x * WPB;

    if (wid >= nseg) return;

    // Prologue: load first segment into xa. Segments tile rows exactly:
    // byte base of segment s is simply s*SEG floats.
    fx4 xa[NV];
    fx4 wxa = {0.0f, 0.0f, 0.0f, 0.0f};
    {
        const fx4* src = (const fx4*)(in + (size_t)wid * SEG);
        #pragma unroll
        for (int k = 0; k < NV; ++k) xa[k] = src[NV * lane + k];
        if ((wid & 7) != 0 && lane < 16) wxa = src[lane - 16];
    }

    for (int s = wid; s < nseg; s += nw) {
        // --- Prefetch next segment (issued before any compute; stays in
        // flight through the whole compute+store of segment s). ---
        const int sn = s + nw;
        fx4 xb[NV] = {};
        fx4 wxb = {0.0f, 0.0f, 0.0f, 0.0f};
        if (sn < nseg) {                       // uniform branch
            const fx4* srcn = (const fx4*)(in + (size_t)sn * SEG);
            #pragma unroll
            for (int k = 0; k < NV; ++k) xb[k] = srcn[NV * lane + k];
            if ((sn & 7) != 0 && lane < 16) wxb = srcn[lane - 16];
        }
        __builtin_amdgcn_sched_barrier(0);     // pin prefetch above compute

        // --- Compute segment s from xa (numerics identical to R7). ---
        // Local contribution of this lane's 16 steps from v=0.
        float c = 0.0f;
        #pragma unroll
        for (int k = 0; k < NV; ++k) {
            c = fmaf(A, c, Bc * xa[k].x);
            c = fmaf(A, c, Bc * xa[k].y);
            c = fmaf(A, c, Bc * xa[k].z);
            c = fmaf(A, c, Bc * xa[k].w);
        }

        // Warm-up: 64-step exact history from v=0 (A^64 truncation, same
        // policy as R3-R8). Lanes 0..15 hold 4 steps each, per-lane decay A^4.
        float vwarm = 0.0f;
        if ((s & 7) != 0) {                    // uniform branch
            float cw;
            cw = Bc * wxa.x;
            cw = fmaf(A, cw, Bc * wxa.y);
            cw = fmaf(A, cw, Bc * wxa.z);
            cw = fmaf(A, cw, Bc * wxa.w);
            float uw;
            uw = __shfl_up(cw, 1); if (lane >= 1) cw = fmaf(A4,  uw, cw);
            uw = __shfl_up(cw, 2); if (lane >= 2) cw = fmaf(A8,  uw, cw);
            uw = __shfl_up(cw, 4); if (lane >= 4) cw = fmaf(A16, uw, cw);
            uw = __shfl_up(cw, 8); if (lane >= 8) cw = fmaf(A32, uw, cw);
            vwarm = __shfl(cw, 15);            // inclusive over 64 warm steps
        }
        if (lane == 0) c = fmaf(A16, vwarm, c);

        // Inclusive affine scan across lanes (uniform per-lane decay A^16).
        float u;
        u = __shfl_up(c, 1); if (lane >= 1) c = fmaf(A16,  u, c);
        u = __shfl_up(c, 2); if (lane >= 2) c = fmaf(A32,  u, c);
        u = __shfl_up(c, 4); if (lane >= 4) c = fmaf(A64,  u, c);
        u = __shfl_up(c, 8); if (lane >= 8) c = fmaf(A128, u, c);

        // v entering this lane's first step = inclusive value of lane-1.
        float venter = __shfl_up(c, 1);
        if (lane == 0) venter = vwarm;

        // Re-run the 16 steps exactly from venter, emitting history in-place.
        float v = venter;
        #pragma unroll
        for (int k = 0; k < NV; ++k) {
            v = fmaf(A, v, Bc * xa[k].x); xa[k].x = v;
            v = fmaf(A, v, Bc * xa[k].y); xa[k].y = v;
            v = fmaf(A, v, Bc * xa[k].z); xa[k].z = v;
            v = fmaf(A, v, Bc * xa[k].w); xa[k].w = v;
        }

        // Coalesced plain stores, mirror of the loads.
        fx4* dst = (fx4*)(out + (size_t)s * SEG);
        #pragma unroll
        for (int k = 0; k < NV; ++k) dst[NV * lane + k] = xa[k];

        // --- Rotate double buffer (vmcnt wait for xb lands here, a full
        // iteration after issue). ---
        #pragma unroll
        for (int k = 0; k < NV; ++k) xa[k] = xb[k];
        wxa = wxb;
    }
}

extern "C" void kernel_launch(void* const* d_in, const int* in_sizes, int n_in,
                              void* d_out, int out_size, void* d_ws, size_t ws_size,
                              hipStream_t stream) {
    const float* in = (const float*)d_in[0];
    float* out = (float*)d_out;
    const int n_rows = in_sizes[0] / TT;          // 4096
    const int nseg = n_rows * (TT / SEG);         // 32768
    int blocks = 1024;                            // 4096 waves, 8 segs/wave
    if (blocks * WPB > nseg) blocks = (nseg + WPB - 1) / WPB;
    neuron_scan<<<dim3(blocks), dim3(BLK), 0, stream>>>(in, out, nseg);
}